// Round 6
// baseline (130.269 us; speedup 1.0000x reference)
//
#include <hip/hip_runtime.h>

typedef __bf16 bf16;
typedef __bf16 bf16x4 __attribute__((ext_vector_type(4)));
typedef __bf16 bf16x8 __attribute__((ext_vector_type(8)));
typedef float  f32x2  __attribute__((ext_vector_type(2)));
typedef float  f32x4  __attribute__((ext_vector_type(4)));

#define MFMA16(a, b, c) __builtin_amdgcn_mfma_f32_16x16x32_bf16((a), (b), (c), 0, 0, 0)

// R26: S2 FROM SUMMED MAIN-GEMM MFMAS (sweep-A/sweep-B restructure).
//  * Identity: s2 = W2*sumMu = sum_k(W2*mu[k]) = sum of the main pass's own
//    MFMA outputs. Each iteration = sweepA {8kt x (2 ds_read + 8 MFMA +
//    s2a[qt]+=a)} + bfly16(s2a) -> s2 lands in the epilogue register layout
//    directly; DELETES per-iter: smS publish+read round-trip (~250cy serial),
//    hi/lo frag build (~60 VALU + 8 DS), 16 chained s2-MFMAs. Init pass
//    drops smv accumulation. Both s2 and a now use the same post-quant bf16
//    mu (more consistent than old pre-quant hi/lo sumMu vs post-quant a).
//  * MFMA pipe 11% -> ~20% (free); serial chain per iter gone.
// Ledger: wave-per-batch, zero barriers, mu bf16 128x64 packed+XOR-swizzled;
// one round (grid 2048, 2 batches/block, weight-init amortized); DPP
// butterflies; f32x2 packed epilogue; base recomputed fp32-exact via shfl.
// Negatives: min-waves>2 spill (R2/4/8); fp32 in-loop global matvec spill
// (R9/12); base-by-MFMA -50% (R18); interleaved dual-batch -40% (R14);
// k-split -30% (R10); LDS-shrink-for-occupancy neutral (R21); xs/ws 16-reg
// preload -> spill (R23); volatile LDS consts -> +21us (R24); bench has
// ~60us fixed overhead above kernel time (R22-R25 analysis).

template<int CTRL>
__device__ __forceinline__ float dpp_add(float v) {
    int t = __builtin_amdgcn_update_dpp(0, __float_as_int(v), CTRL, 0xF, 0xF, false);
    return v + __int_as_float(t);
}

__device__ __forceinline__ void bfly16(f32x2* s) {
#pragma unroll
    for (int i = 0; i < 8; ++i) { s[i][0] = dpp_add<0x121>(s[i][0]); s[i][1] = dpp_add<0x121>(s[i][1]); }
#pragma unroll
    for (int i = 0; i < 8; ++i) { s[i][0] = dpp_add<0x122>(s[i][0]); s[i][1] = dpp_add<0x122>(s[i][1]); }
#pragma unroll
    for (int i = 0; i < 8; ++i) { s[i][0] = dpp_add<0x124>(s[i][0]); s[i][1] = dpp_add<0x124>(s[i][1]); }
#pragma unroll
    for (int i = 0; i < 8; ++i) { s[i][0] = dpp_add<0x128>(s[i][0]); s[i][1] = dpp_add<0x128>(s[i][1]); }
}

__device__ __forceinline__ f32x2 fma2(f32x2 a, f32x2 b, f32x2 c) {
    return __builtin_elementwise_fma(a, b, c);
}
__device__ __forceinline__ f32x2 max2(f32x2 a, f32x2 b) {
    return __builtin_elementwise_max(a, b);
}

__global__ __launch_bounds__(64, 2)
void qnet_kernel(const float* __restrict__ Xg, const float* __restrict__ Wg,
                 const float* __restrict__ W1g, const float* __restrict__ W2g,
                 const float* __restrict__ W3g, const float* __restrict__ W4g,
                 const float* __restrict__ W5g, const float* __restrict__ W6g,
                 const float* __restrict__ W7g, float* __restrict__ Outg)
{
    __shared__ __align__(16) bf16 muS[128 * 64];   // 16384 B, packed + swizzled
    __shared__ __align__(16) float uS[64];         // 256 B  (weight-only)
    __shared__ __align__(16) float smS[64];        // 256 B  readout broadcast only

    const int lane = threadIdx.x;       // 0..63, one wave
    const int l15  = lane & 15;
    const int quad = lane >> 4;
    const int sw   = l15 & 7;           // swizzle key: k&7 == l15&7 for k=16kt+l15

    // ================= weight-only init (amortized over 2 batches) =================
    float sp = 0.f, sm = 0.f;
#pragma unroll
    for (int c = 0; c < 16; ++c) {
        f32x4 w4 = *(const f32x4*)&W4g[c * 4];
        f32x4 w3 = *(const f32x4*)&W3g[lane * 64 + c * 4];
#pragma unroll
        for (int e = 0; e < 4; ++e) {
            sp += fmaxf(w4[e], 0.f) * w3[e];
            sm += fmaxf(-w4[e], 0.f) * w3[e];
        }
    }
    f32x2 w1P[4][2], v3pP[4][2], v3mP[4][2];
#pragma unroll
    for (int qt = 0; qt < 4; ++qt) {
        f32x4 w1v = *(const f32x4*)&W1g[qt * 16 + quad * 4];
#pragma unroll
        for (int e = 0; e < 4; ++e) {
            const int q = qt * 16 + quad * 4 + e;
            v3pP[qt][e >> 1][e & 1] = __shfl(sp, q);
            v3mP[qt][e >> 1][e & 1] = __shfl(sm, q);
            w1P[qt][e >> 1][e & 1]  = w1v[e];
        }
    }

    // u[p=lane] = W5b @ W7[:,p] -> uS (weight-only, written once)
    {
        float u = 0.f;
#pragma unroll
        for (int c = 0; c < 16; ++c) {
            f32x4 w5v = *(const f32x4*)&W5g[64 + c * 4];
#pragma unroll
            for (int e = 0; e < 4; ++e) u += w5v[e] * W7g[(c * 4 + e) * 64 + lane];
        }
        uS[lane] = u;
    }

    // W2 A-fragments (bf16 hi only)
    bf16x8 w2h[4][2];
#pragma unroll
    for (int qt = 0; qt < 4; ++qt)
#pragma unroll
        for (int s = 0; s < 2; ++s) {
            const float* src = &W2g[(qt * 16 + l15) * 64 + s * 32 + quad * 8];
            f32x4 f0 = *(const f32x4*)src;
            f32x4 f1 = *(const f32x4*)(src + 4);
            bf16x8 h;
#pragma unroll
            for (int e = 0; e < 4; ++e) { h[e] = (bf16)f0[e]; h[4 + e] = (bf16)f1[e]; }
            w2h[qt][s] = h;
        }

    const f32x2 zz = {0.f, 0.f};
    const f32x4 zero4 = {0.f, 0.f, 0.f, 0.f};

    // ================= 2 batches, sequential =================
#pragma unroll 1
    for (int bi = 0; bi < 2; ++bi) {
        const int b = blockIdx.x * 2 + bi;

        // per-batch vectors (6 persistent regs, R22 form)
        float xv0 = Xg[b * 128 + lane], xv1 = Xg[b * 128 + 64 + lane];
        float wv0 = Wg[b * 128 + lane], wv1 = Wg[b * 128 + 64 + lane];

        float Ap = fmaxf(wv0, 0.f) + fmaxf(wv1, 0.f);
        float Bn = fmaxf(-wv0, 0.f) + fmaxf(-wv1, 0.f);
#pragma unroll
        for (int m = 1; m < 64; m <<= 1) { Ap += __shfl_xor(Ap, m); Bn += __shfl_xor(Bn, m); }

        // ---------------- mu1 = relu(base), exact fp32 (no smv needed) ----------------
#pragma unroll
        for (int kt = 0; kt < 8; ++kt) {
            const int src = (kt & 3) * 16 + l15;
            float xs_ = __shfl((kt < 4) ? xv0 : xv1, src);
            float ws_ = __shfl((kt < 4) ? wv0 : wv1, src);
            f32x2 xs2 = {xs_, xs_};
            float ap_ = Ap - fmaxf(ws_, 0.f);
            float bn_ = Bn - fmaxf(-ws_, 0.f);
            f32x2 ap2 = {ap_, ap_}, bn2 = {bn_, bn_};
            const int row = (kt * 16 + l15) * 64;
#pragma unroll
            for (int qt = 0; qt < 4; ++qt) {
                f32x2 t01 = fma2(ap2, v3pP[qt][0], bn2 * v3mP[qt][0]);
                t01 = fma2(xs2, w1P[qt][0], t01);
                f32x2 v01 = max2(t01, zz);
                f32x2 t23 = fma2(ap2, v3pP[qt][1], bn2 * v3mP[qt][1]);
                t23 = fma2(xs2, w1P[qt][1], t23);
                f32x2 v23 = max2(t23, zz);
                bf16x4 h = {(bf16)v01[0], (bf16)v01[1], (bf16)v23[0], (bf16)v23[1]};
                *(bf16x4*)&muS[row + ((2 * qt + (quad >> 1)) ^ sw) * 8 + 4 * (quad & 1)] = h;
            }
        }

        // ---------------- 3 iterations, zero barriers ----------------
        f32x2 smv2[8];
#pragma unroll
        for (int i = 0; i < 8; ++i) smv2[i] = zz;

        for (int it = 0; it < 3; ++it) {
            // sweep A: s2a[qt] = sum_k W2·mu_t[k]  (pure MFMA+read stream)
            f32x4 s2a[4];
#pragma unroll
            for (int qt = 0; qt < 4; ++qt) s2a[qt] = zero4;
#pragma unroll
            for (int kt = 0; kt < 8; ++kt) {
                const int row = (kt * 16 + l15) * 64;
                bf16x8 m0 = *(const bf16x8*)&muS[row + ((quad) ^ sw) * 8];
                bf16x8 m1 = *(const bf16x8*)&muS[row + ((4 + quad) ^ sw) * 8];
#pragma unroll
                for (int qt = 0; qt < 4; ++qt) {
                    f32x4 a = MFMA16(w2h[qt][0], m0, zero4);
                    a = MFMA16(w2h[qt][1], m1, a);
                    s2a[qt] += a;
                }
            }
            // sum over the 16 l15 k-rows; result lands in epilogue layout:
            // s2a[qt][e] = s2[q = qt*16 + quad*4 + e] in every lane
            bfly16((f32x2*)s2a);

            // sweep B: 64 MFMAs + packed-fp32 fused epilogue
#pragma unroll
            for (int i = 0; i < 8; ++i) smv2[i] = zz;
#pragma unroll
            for (int kt = 0; kt < 8; ++kt) {
                const int src = (kt & 3) * 16 + l15;
                float xs_ = __shfl((kt < 4) ? xv0 : xv1, src);
                float ws_ = __shfl((kt < 4) ? wv0 : wv1, src);
                f32x2 xs2 = {xs_, xs_};
                float ap_ = Ap - fmaxf(ws_, 0.f);
                float bn_ = Bn - fmaxf(-ws_, 0.f);
                f32x2 ap2 = {ap_, ap_}, bn2 = {bn_, bn_};
                const int row = (kt * 16 + l15) * 64;
                bf16x8 m0 = *(const bf16x8*)&muS[row + ((quad) ^ sw) * 8];
                bf16x8 m1 = *(const bf16x8*)&muS[row + ((4 + quad) ^ sw) * 8];
#pragma unroll
                for (int qt = 0; qt < 4; ++qt) {
                    f32x4 a = MFMA16(w2h[qt][0], m0, zero4);
                    a = MFMA16(w2h[qt][1], m1, a);
                    f32x2 a01 = __builtin_shufflevector(a, a, 0, 1);
                    f32x2 a23 = __builtin_shufflevector(a, a, 2, 3);
                    f32x2 s01 = __builtin_shufflevector(s2a[qt], s2a[qt], 0, 1);
                    f32x2 s23 = __builtin_shufflevector(s2a[qt], s2a[qt], 2, 3);
                    f32x2 t01 = fma2(xs2, w1P[qt][0], s01);
                    t01 = fma2(ap2, v3pP[qt][0], t01);
                    t01 = fma2(bn2, v3mP[qt][0], t01);
                    f32x2 v01 = max2(t01 - a01, zz);
                    f32x2 t23 = fma2(xs2, w1P[qt][1], s23);
                    t23 = fma2(ap2, v3pP[qt][1], t23);
                    t23 = fma2(bn2, v3mP[qt][1], t23);
                    f32x2 v23 = max2(t23 - a23, zz);
                    smv2[qt * 2]     += v01;
                    smv2[qt * 2 + 1] += v23;
                    bf16x4 h = {(bf16)v01[0], (bf16)v01[1], (bf16)v23[0], (bf16)v23[1]};
                    *(bf16x4*)&muS[row + ((2 * qt + (quad >> 1)) ^ sw) * 8 + 4 * (quad & 1)] = h;
                }
            }
        }

        // ---------------- readout (wave-internal) ----------------
        bfly16(smv2);
        if (l15 == 0) {
#pragma unroll
            for (int qt = 0; qt < 4; ++qt) {
                f32x4 v = {smv2[qt * 2][0], smv2[qt * 2][1],
                           smv2[qt * 2 + 1][0], smv2[qt * 2 + 1][1]};
                *(f32x4*)&smS[qt * 16 + quad * 4] = v;
            }
        }

        float pl = 0.f;
#pragma unroll
        for (int c = 0; c < 16; ++c) {
            f32x4 sv = *(const f32x4*)&smS[c * 4];
            f32x4 w6 = *(const f32x4*)&W6g[lane * 64 + c * 4];
#pragma unroll
            for (int e = 0; e < 4; ++e) pl = fmaf(sv[e], w6[e], pl);
        }
        float qa = fmaxf(pl, 0.f) * W5g[lane];
#pragma unroll
        for (int m = 1; m < 64; m <<= 1) qa += __shfl_xor(qa, m);

        f32x4 uf[2][2];
#pragma unroll
        for (int s = 0; s < 2; ++s) {
            uf[s][0] = *(const f32x4*)&uS[s * 32 + quad * 8];
            uf[s][1] = *(const f32x4*)&uS[s * 32 + quad * 8 + 4];
        }

        float res[8];
#pragma unroll
        for (int kt = 0; kt < 8; ++kt) {
            const int row = (kt * 16 + l15) * 64;
            bf16x8 m0 = *(const bf16x8*)&muS[row + ((quad) ^ sw) * 8];
            bf16x8 m1 = *(const bf16x8*)&muS[row + ((4 + quad) ^ sw) * 8];
            float r = 0.f;
#pragma unroll
            for (int j = 0; j < 4; ++j) {
                r = fmaf((float)m0[j],     uf[0][0][j], r);
                r = fmaf((float)m0[4 + j], uf[0][1][j], r);
                r = fmaf((float)m1[j],     uf[1][0][j], r);
                r = fmaf((float)m1[4 + j], uf[1][1][j], r);
            }
            r += __shfl_xor(r, 16); r += __shfl_xor(r, 32);
            res[kt] = r;
        }
        float rA0 = (quad & 1) ? res[1] : res[0];
        float rA1 = (quad & 1) ? res[3] : res[2];
        float rA  = (quad & 2) ? rA1 : rA0;
        float rB0 = (quad & 1) ? res[5] : res[4];
        float rB1 = (quad & 1) ? res[7] : res[6];
        float rB  = (quad & 2) ? rB1 : rB0;
        Outg[b * 128 + lane]      = qa + rA;   // k = lane       (kt = quad)
        Outg[b * 128 + 64 + lane] = qa + rB;   // k = lane + 64  (kt = quad + 4)
    }
}

extern "C" void kernel_launch(void* const* d_in, const int* in_sizes, int n_in,
                              void* d_out, int out_size, void* d_ws, size_t ws_size,
                              hipStream_t stream) {
    (void)n_in; (void)d_ws; (void)ws_size; (void)out_size;
    const int B = in_sizes[0] >> 7;   // 4096
    qnet_kernel<<<B / 2, 64, 0, stream>>>(
        (const float*)d_in[0], (const float*)d_in[1], (const float*)d_in[2],
        (const float*)d_in[3], (const float*)d_in[4], (const float*)d_in[5],
        (const float*)d_in[6], (const float*)d_in[7], (const float*)d_in[8],
        (float*)d_out);
}

// Round 7
// 117.003 us; speedup vs baseline: 1.1134x; 1.1134x over previous
//
#include <hip/hip_runtime.h>

typedef __bf16 bf16;
typedef __bf16 bf16x4 __attribute__((ext_vector_type(4)));
typedef __bf16 bf16x8 __attribute__((ext_vector_type(8)));
typedef float  f32x2  __attribute__((ext_vector_type(2)));
typedef float  f32x4  __attribute__((ext_vector_type(4)));

#define MFMA16(a, b, c) __builtin_amdgcn_mfma_f32_16x16x32_bf16((a), (b), (c), 0, 0, 0)

// R27: R25 REVERT + FINAL-ITERATION FUSED READOUT.
//  * R26 postmortem: sweep-A s2 restructure added 16+ live regs -> 128 cliff,
//    40MB scratch traffic, 99us. RULE: any variant adding >=16 live regs to
//    the iteration body spills (R23/R26; R14/R9 consistent). REVERTED to R25.
//  * This round: iteration 3's mu values are consumed in-register by the
//    local-readout (res[k] = sum_q mu[k,q]*u[q] via 8 pk-FMA/kt against
//    pre-distributed uP), deleting: 32 final mu ds_writes, 16 readout mu
//    ds_reads, uS staging (+2 reads), 128 cvt + 128 scalar FMA. rA/rB
//    selected per-kt by cndmask (2 regs, not res[8]). Register-audited ~117.
// Ledger: wave-per-batch, zero barriers, mu bf16 128x64 packed+XOR-swizzled;
// one round (grid 2048, 2 batches/block, weight-init amortized); DPP
// butterflies; s2 via smS publish + hi/lo broadcast-frag MFMAs; f32x2 packed
// epilogue; base recomputed fp32-exact via shfl.
// Negatives: min-waves>2 spill (R2/4/8); fp32 in-loop global matvec spill
// (R9/12); base-by-MFMA -50% (R18); interleaved dual-batch -40% (R14);
// k-split -30% (R10); LDS-shrink-for-occupancy neutral (R21); xs/ws 16-reg
// preload spill (R23); volatile LDS consts +21us (R24); s2-from-main-MFMA
// sweep spill (R26); bench has ~60us fixed overhead above kernel time.

template<int CTRL>
__device__ __forceinline__ float dpp_add(float v) {
    int t = __builtin_amdgcn_update_dpp(0, __float_as_int(v), CTRL, 0xF, 0xF, false);
    return v + __int_as_float(t);
}

__device__ __forceinline__ void bfly16(f32x2* s) {
#pragma unroll
    for (int i = 0; i < 8; ++i) { s[i][0] = dpp_add<0x121>(s[i][0]); s[i][1] = dpp_add<0x121>(s[i][1]); }
#pragma unroll
    for (int i = 0; i < 8; ++i) { s[i][0] = dpp_add<0x122>(s[i][0]); s[i][1] = dpp_add<0x122>(s[i][1]); }
#pragma unroll
    for (int i = 0; i < 8; ++i) { s[i][0] = dpp_add<0x124>(s[i][0]); s[i][1] = dpp_add<0x124>(s[i][1]); }
#pragma unroll
    for (int i = 0; i < 8; ++i) { s[i][0] = dpp_add<0x128>(s[i][0]); s[i][1] = dpp_add<0x128>(s[i][1]); }
}

__device__ __forceinline__ f32x2 fma2(f32x2 a, f32x2 b, f32x2 c) {
    return __builtin_elementwise_fma(a, b, c);
}
__device__ __forceinline__ f32x2 max2(f32x2 a, f32x2 b) {
    return __builtin_elementwise_max(a, b);
}

__global__ __launch_bounds__(64, 2)
void qnet_kernel(const float* __restrict__ Xg, const float* __restrict__ Wg,
                 const float* __restrict__ W1g, const float* __restrict__ W2g,
                 const float* __restrict__ W3g, const float* __restrict__ W4g,
                 const float* __restrict__ W5g, const float* __restrict__ W6g,
                 const float* __restrict__ W7g, float* __restrict__ Outg)
{
    __shared__ __align__(16) bf16 muS[128 * 64];   // 16384 B, packed + swizzled
    __shared__ __align__(16) float smS[64];        // 256 B  sumMu broadcast

    const int lane = threadIdx.x;       // 0..63, one wave
    const int l15  = lane & 15;
    const int quad = lane >> 4;
    const int sw   = l15 & 7;           // swizzle key: k&7 == l15&7 for k=16kt+l15

    // ================= weight-only init (amortized over 2 batches) =================
    float sp = 0.f, sm = 0.f;
#pragma unroll
    for (int c = 0; c < 16; ++c) {
        f32x4 w4 = *(const f32x4*)&W4g[c * 4];
        f32x4 w3 = *(const f32x4*)&W3g[lane * 64 + c * 4];
#pragma unroll
        for (int e = 0; e < 4; ++e) {
            sp += fmaxf(w4[e], 0.f) * w3[e];
            sm += fmaxf(-w4[e], 0.f) * w3[e];
        }
    }
    f32x2 w1P[4][2], v3pP[4][2], v3mP[4][2];
#pragma unroll
    for (int qt = 0; qt < 4; ++qt) {
        f32x4 w1v = *(const f32x4*)&W1g[qt * 16 + quad * 4];
#pragma unroll
        for (int e = 0; e < 4; ++e) {
            const int q = qt * 16 + quad * 4 + e;
            v3pP[qt][e >> 1][e & 1] = __shfl(sp, q);
            v3mP[qt][e >> 1][e & 1] = __shfl(sm, q);
            w1P[qt][e >> 1][e & 1]  = w1v[e];
        }
    }

    // u[p=lane] = W5b @ W7[:,p]  (kept in ONE register; distributed later)
    float u = 0.f;
#pragma unroll
    for (int c = 0; c < 16; ++c) {
        f32x4 w5v = *(const f32x4*)&W5g[64 + c * 4];
#pragma unroll
        for (int e = 0; e < 4; ++e) u += w5v[e] * W7g[(c * 4 + e) * 64 + lane];
    }

    // W2 A-fragments (bf16 hi only)
    bf16x8 w2h[4][2];
#pragma unroll
    for (int qt = 0; qt < 4; ++qt)
#pragma unroll
        for (int s = 0; s < 2; ++s) {
            const float* src = &W2g[(qt * 16 + l15) * 64 + s * 32 + quad * 8];
            f32x4 f0 = *(const f32x4*)src;
            f32x4 f1 = *(const f32x4*)(src + 4);
            bf16x8 h;
#pragma unroll
            for (int e = 0; e < 4; ++e) { h[e] = (bf16)f0[e]; h[4 + e] = (bf16)f1[e]; }
            w2h[qt][s] = h;
        }

    const f32x2 zz = {0.f, 0.f};
    const f32x4 zero4 = {0.f, 0.f, 0.f, 0.f};

    // ================= 2 batches, sequential =================
#pragma unroll 1
    for (int bi = 0; bi < 2; ++bi) {
        const int b = blockIdx.x * 2 + bi;

        // per-batch vectors (6 persistent regs)
        float xv0 = Xg[b * 128 + lane], xv1 = Xg[b * 128 + 64 + lane];
        float wv0 = Wg[b * 128 + lane], wv1 = Wg[b * 128 + 64 + lane];

        float Ap = fmaxf(wv0, 0.f) + fmaxf(wv1, 0.f);
        float Bn = fmaxf(-wv0, 0.f) + fmaxf(-wv1, 0.f);
#pragma unroll
        for (int m = 1; m < 64; m <<= 1) { Ap += __shfl_xor(Ap, m); Bn += __shfl_xor(Bn, m); }

        // ---------------- mu1 = relu(base), exact fp32; accumulate smv ----------------
        f32x2 smv2[8];
#pragma unroll
        for (int i = 0; i < 8; ++i) smv2[i] = zz;
#pragma unroll
        for (int kt = 0; kt < 8; ++kt) {
            const int src = (kt & 3) * 16 + l15;
            float xs_ = __shfl((kt < 4) ? xv0 : xv1, src);
            float ws_ = __shfl((kt < 4) ? wv0 : wv1, src);
            f32x2 xs2 = {xs_, xs_};
            float ap_ = Ap - fmaxf(ws_, 0.f);
            float bn_ = Bn - fmaxf(-ws_, 0.f);
            f32x2 ap2 = {ap_, ap_}, bn2 = {bn_, bn_};
            const int row = (kt * 16 + l15) * 64;
#pragma unroll
            for (int qt = 0; qt < 4; ++qt) {
                f32x2 t01 = fma2(ap2, v3pP[qt][0], bn2 * v3mP[qt][0]);
                t01 = fma2(xs2, w1P[qt][0], t01);
                f32x2 v01 = max2(t01, zz);
                f32x2 t23 = fma2(ap2, v3pP[qt][1], bn2 * v3mP[qt][1]);
                t23 = fma2(xs2, w1P[qt][1], t23);
                f32x2 v23 = max2(t23, zz);
                smv2[qt * 2]     += v01;
                smv2[qt * 2 + 1] += v23;
                bf16x4 h = {(bf16)v01[0], (bf16)v01[1], (bf16)v23[0], (bf16)v23[1]};
                *(bf16x4*)&muS[row + ((2 * qt + (quad >> 1)) ^ sw) * 8 + 4 * (quad & 1)] = h;
            }
        }

        // ---------------- iterations 1..2 (write-back form), zero barriers ----------------
#pragma unroll 1
        for (int it = 0; it < 2; ++it) {
            bfly16(smv2);
            if (l15 == 0) {
#pragma unroll
                for (int qt = 0; qt < 4; ++qt) {
                    f32x4 v = {smv2[qt * 2][0], smv2[qt * 2][1],
                               smv2[qt * 2 + 1][0], smv2[qt * 2 + 1][1]};
                    *(f32x4*)&smS[qt * 16 + quad * 4] = v;
                }
            }
            bf16x8 bh0, bl0, bh1, bl1;
            {
                f32x4 pA = *(const f32x4*)&smS[quad * 8];
                f32x4 pB = *(const f32x4*)&smS[quad * 8 + 4];
#pragma unroll
                for (int e = 0; e < 4; ++e) {
                    bf16 h = (bf16)pA[e]; bh0[e] = h;     bl0[e] = (bf16)(pA[e] - (float)h);
                    bf16 g = (bf16)pB[e]; bh0[4 + e] = g; bl0[4 + e] = (bf16)(pB[e] - (float)g);
                }
                pA = *(const f32x4*)&smS[32 + quad * 8];
                pB = *(const f32x4*)&smS[32 + quad * 8 + 4];
#pragma unroll
                for (int e = 0; e < 4; ++e) {
                    bf16 h = (bf16)pA[e]; bh1[e] = h;     bl1[e] = (bf16)(pA[e] - (float)h);
                    bf16 g = (bf16)pB[e]; bh1[4 + e] = g; bl1[4 + e] = (bf16)(pB[e] - (float)g);
                }
            }
            f32x2 s2p[4][2];
#pragma unroll
            for (int qt = 0; qt < 4; ++qt) {
                f32x4 a = MFMA16(w2h[qt][0], bh0, zero4);
                a = MFMA16(w2h[qt][1], bh1, a);
                a = MFMA16(w2h[qt][0], bl0, a);
                a = MFMA16(w2h[qt][1], bl1, a);
                s2p[qt][0] = __builtin_shufflevector(a, a, 0, 1);
                s2p[qt][1] = __builtin_shufflevector(a, a, 2, 3);
            }

#pragma unroll
            for (int i = 0; i < 8; ++i) smv2[i] = zz;
#pragma unroll
            for (int kt = 0; kt < 8; ++kt) {
                const int src = (kt & 3) * 16 + l15;
                float xs_ = __shfl((kt < 4) ? xv0 : xv1, src);
                float ws_ = __shfl((kt < 4) ? wv0 : wv1, src);
                f32x2 xs2 = {xs_, xs_};
                float ap_ = Ap - fmaxf(ws_, 0.f);
                float bn_ = Bn - fmaxf(-ws_, 0.f);
                f32x2 ap2 = {ap_, ap_}, bn2 = {bn_, bn_};
                const int row = (kt * 16 + l15) * 64;
                bf16x8 m0 = *(const bf16x8*)&muS[row + ((quad) ^ sw) * 8];
                bf16x8 m1 = *(const bf16x8*)&muS[row + ((4 + quad) ^ sw) * 8];
#pragma unroll
                for (int qt = 0; qt < 4; ++qt) {
                    f32x4 a = MFMA16(w2h[qt][0], m0, zero4);
                    a = MFMA16(w2h[qt][1], m1, a);
                    f32x2 a01 = __builtin_shufflevector(a, a, 0, 1);
                    f32x2 a23 = __builtin_shufflevector(a, a, 2, 3);
                    f32x2 t01 = fma2(xs2, w1P[qt][0], s2p[qt][0]);
                    t01 = fma2(ap2, v3pP[qt][0], t01);
                    t01 = fma2(bn2, v3mP[qt][0], t01);
                    f32x2 v01 = max2(t01 - a01, zz);
                    f32x2 t23 = fma2(xs2, w1P[qt][1], s2p[qt][1]);
                    t23 = fma2(ap2, v3pP[qt][1], t23);
                    t23 = fma2(bn2, v3mP[qt][1], t23);
                    f32x2 v23 = max2(t23 - a23, zz);
                    smv2[qt * 2]     += v01;
                    smv2[qt * 2 + 1] += v23;
                    bf16x4 h = {(bf16)v01[0], (bf16)v01[1], (bf16)v23[0], (bf16)v23[1]};
                    *(bf16x4*)&muS[row + ((2 * qt + (quad >> 1)) ^ sw) * 8 + 4 * (quad & 1)] = h;
                }
            }
        }

        // ---------------- final iteration: fused with local readout, no mu writes ----------------
        bfly16(smv2);
        if (l15 == 0) {
#pragma unroll
            for (int qt = 0; qt < 4; ++qt) {
                f32x4 v = {smv2[qt * 2][0], smv2[qt * 2][1],
                           smv2[qt * 2 + 1][0], smv2[qt * 2 + 1][1]};
                *(f32x4*)&smS[qt * 16 + quad * 4] = v;
            }
        }
        bf16x8 bh0, bl0, bh1, bl1;
        {
            f32x4 pA = *(const f32x4*)&smS[quad * 8];
            f32x4 pB = *(const f32x4*)&smS[quad * 8 + 4];
#pragma unroll
            for (int e = 0; e < 4; ++e) {
                bf16 h = (bf16)pA[e]; bh0[e] = h;     bl0[e] = (bf16)(pA[e] - (float)h);
                bf16 g = (bf16)pB[e]; bh0[4 + e] = g; bl0[4 + e] = (bf16)(pB[e] - (float)g);
            }
            pA = *(const f32x4*)&smS[32 + quad * 8];
            pB = *(const f32x4*)&smS[32 + quad * 8 + 4];
#pragma unroll
            for (int e = 0; e < 4; ++e) {
                bf16 h = (bf16)pA[e]; bh1[e] = h;     bl1[e] = (bf16)(pA[e] - (float)h);
                bf16 g = (bf16)pB[e]; bh1[4 + e] = g; bl1[4 + e] = (bf16)(pB[e] - (float)g);
            }
        }
        f32x2 s2p[4][2];
#pragma unroll
        for (int qt = 0; qt < 4; ++qt) {
            f32x4 a = MFMA16(w2h[qt][0], bh0, zero4);
            a = MFMA16(w2h[qt][1], bh1, a);
            a = MFMA16(w2h[qt][0], bl0, a);
            a = MFMA16(w2h[qt][1], bl1, a);
            s2p[qt][0] = __builtin_shufflevector(a, a, 0, 1);
            s2p[qt][1] = __builtin_shufflevector(a, a, 2, 3);
        }

        // distribute u into epilogue (qt,pair) layout: uP[qt][p2][e2] = u[q]
        f32x2 uP[4][2];
#pragma unroll
        for (int qt = 0; qt < 4; ++qt)
#pragma unroll
            for (int e = 0; e < 4; ++e)
                uP[qt][e >> 1][e & 1] = __shfl(u, qt * 16 + quad * 4 + e);

        float rA = 0.f, rB = 0.f;
#pragma unroll
        for (int i = 0; i < 8; ++i) smv2[i] = zz;
#pragma unroll
        for (int kt = 0; kt < 8; ++kt) {
            const int src = (kt & 3) * 16 + l15;
            float xs_ = __shfl((kt < 4) ? xv0 : xv1, src);
            float ws_ = __shfl((kt < 4) ? wv0 : wv1, src);
            f32x2 xs2 = {xs_, xs_};
            float ap_ = Ap - fmaxf(ws_, 0.f);
            float bn_ = Bn - fmaxf(-ws_, 0.f);
            f32x2 ap2 = {ap_, ap_}, bn2 = {bn_, bn_};
            const int row = (kt * 16 + l15) * 64;
            bf16x8 m0 = *(const bf16x8*)&muS[row + ((quad) ^ sw) * 8];
            bf16x8 m1 = *(const bf16x8*)&muS[row + ((4 + quad) ^ sw) * 8];
            f32x2 racc = zz;
#pragma unroll
            for (int qt = 0; qt < 4; ++qt) {
                f32x4 a = MFMA16(w2h[qt][0], m0, zero4);
                a = MFMA16(w2h[qt][1], m1, a);
                f32x2 a01 = __builtin_shufflevector(a, a, 0, 1);
                f32x2 a23 = __builtin_shufflevector(a, a, 2, 3);
                f32x2 t01 = fma2(xs2, w1P[qt][0], s2p[qt][0]);
                t01 = fma2(ap2, v3pP[qt][0], t01);
                t01 = fma2(bn2, v3mP[qt][0], t01);
                f32x2 v01 = max2(t01 - a01, zz);
                f32x2 t23 = fma2(xs2, w1P[qt][1], s2p[qt][1]);
                t23 = fma2(ap2, v3pP[qt][1], t23);
                t23 = fma2(bn2, v3mP[qt][1], t23);
                f32x2 v23 = max2(t23 - a23, zz);
                smv2[qt * 2]     += v01;
                smv2[qt * 2 + 1] += v23;
                racc = fma2(v01, uP[qt][0], racc);
                racc = fma2(v23, uP[qt][1], racc);
            }
            float r = racc[0] + racc[1];
            r += __shfl_xor(r, 16); r += __shfl_xor(r, 32);
            rA = (quad == kt)     ? r : rA;
            rB = (quad == kt - 4) ? r : rB;
        }

        // ---------------- pooled readout ----------------
        bfly16(smv2);
        if (l15 == 0) {
#pragma unroll
            for (int qt = 0; qt < 4; ++qt) {
                f32x4 v = {smv2[qt * 2][0], smv2[qt * 2][1],
                           smv2[qt * 2 + 1][0], smv2[qt * 2 + 1][1]};
                *(f32x4*)&smS[qt * 16 + quad * 4] = v;
            }
        }

        float pl = 0.f;
#pragma unroll
        for (int c = 0; c < 16; ++c) {
            f32x4 sv = *(const f32x4*)&smS[c * 4];
            f32x4 w6 = *(const f32x4*)&W6g[lane * 64 + c * 4];
#pragma unroll
            for (int e = 0; e < 4; ++e) pl = fmaf(sv[e], w6[e], pl);
        }
        float qa = fmaxf(pl, 0.f) * W5g[lane];
#pragma unroll
        for (int m = 1; m < 64; m <<= 1) qa += __shfl_xor(qa, m);

        Outg[b * 128 + lane]      = qa + rA;   // k = lane       (kt = quad)
        Outg[b * 128 + 64 + lane] = qa + rB;   // k = lane + 64  (kt = quad + 4)
    }
}

extern "C" void kernel_launch(void* const* d_in, const int* in_sizes, int n_in,
                              void* d_out, int out_size, void* d_ws, size_t ws_size,
                              hipStream_t stream) {
    (void)n_in; (void)d_ws; (void)ws_size; (void)out_size;
    const int B = in_sizes[0] >> 7;   // 4096
    qnet_kernel<<<B / 2, 64, 0, stream>>>(
        (const float*)d_in[0], (const float*)d_in[1], (const float*)d_in[2],
        (const float*)d_in[3], (const float*)d_in[4], (const float*)d_in[5],
        (const float*)d_in[6], (const float*)d_in[7], (const float*)d_in[8],
        (float*)d_out);
}